// Round 10
// baseline (1715.409 us; speedup 1.0000x reference)
//
#include <hip/hip_runtime.h>

#define B_ 128
#define T_ 256
#define IN_ 256
#define H_ 512
#define G4_ 2048   // 4*H
#define TC_ 16     // time chunk
#define TC_LOG_ 4
#define NCHUNK_ 16

typedef __attribute__((ext_vector_type(8))) short short8v;   // 8 bf16
typedef __attribute__((ext_vector_type(4))) float float4v;

// ---- workspace layout (float offsets) ---- (~61MB total)
static constexpr size_t OFF_XG0 = 0;                                  // B*TC*4H fp32
static constexpr size_t OFF_XG1 = OFF_XG0 + (size_t)B_ * TC_ * G4_;
static constexpr size_t OFF_H0C = OFF_XG1 + (size_t)B_ * TC_ * G4_;   // B*TC*H bf16
static constexpr size_t OFF_HB0 = OFF_H0C + (size_t)B_ * TC_ * H_ / 2;// 2 slots B*H bf16
static constexpr size_t OFF_HB1 = OFF_HB0 + (size_t)B_ * H_;
static constexpr size_t OFF_C0  = OFF_HB1 + (size_t)B_ * H_;          // B*H fp32
static constexpr size_t OFF_C1  = OFF_C0 + (size_t)B_ * H_;
static constexpr size_t OFF_H1F = OFF_C1 + (size_t)B_ * H_;           // B*H fp32
static constexpr size_t OFF_WF0 = OFF_H1F + (size_t)B_ * H_;          // W_hh0 bf16 frags
static constexpr size_t OFF_WF1 = OFF_WF0 + (size_t)G4_ * H_ / 2;
static constexpr size_t OFF_WI0 = OFF_WF1 + (size_t)G4_ * H_ / 2;     // W_ih0 bf16 frags (K=256)
static constexpr size_t OFF_WI1 = OFF_WI0 + (size_t)G4_ * IN_ / 2;    // W_ih1 bf16 frags (K=512)
static constexpr size_t OFF_XBF = OFF_WI1 + (size_t)G4_ * H_ / 2;     // x bf16
static constexpr size_t OFF_END = OFF_XBF + (size_t)B_ * T_ * IN_ / 2;

// bf16 round-to-nearest-even from fp32
__device__ __forceinline__ unsigned int bfr(float f) {
  unsigned int u = __float_as_uint(f);
  return (u + 0x7fffu + ((u >> 16) & 1u)) >> 16;
}

// ============================================================================
// Convert fp32 -> bf16, 8 elems/thread (for x).
// ============================================================================
__global__ __launch_bounds__(256) void conv_bf16(
    const float* __restrict__ in, uint4* __restrict__ out, int n8) {
  const int idx = blockIdx.x * 256 + threadIdx.x;
  if (idx >= n8) return;
  const float4 a = *(const float4*)(in + (size_t)idx * 8);
  const float4 b = *(const float4*)(in + (size_t)idx * 8 + 4);
  uint4 o;
  o.x = bfr(a.x) | (bfr(a.y) << 16);
  o.y = bfr(a.z) | (bfr(a.w) << 16);
  o.z = bfr(b.x) | (bfr(b.y) << 16);
  o.w = bfr(b.z) | (bfr(b.w) << 16);
  out[idx] = o;
}

// ============================================================================
// Pack W_hh [2048][512] fp32 -> bf16 MFMA B-fragments, gate-tiled order
// (ct,g,ks): lane l holds W[g*512+ct*16+(l&15)][ks*32+(l>>4)*8 .. +7].
// ============================================================================
__global__ __launch_bounds__(256) void pack_whh3(
    const float* __restrict__ W, uint4* __restrict__ WF) {
  const int idx = blockIdx.x * 256 + threadIdx.x;  // 0..131071
  const int l  = idx & 63;
  const int ks = (idx >> 6) & 15;
  const int g  = (idx >> 10) & 3;
  const int ct = idx >> 12;                        // 0..31
  const int row = g * H_ + ct * 16 + (l & 15);
  const int k0  = ks * 32 + (l >> 4) * 8;
  const float* s = W + (size_t)row * H_ + k0;
  uint4 o;
  o.x = bfr(s[0]) | (bfr(s[1]) << 16);
  o.y = bfr(s[2]) | (bfr(s[3]) << 16);
  o.z = bfr(s[4]) | (bfr(s[5]) << 16);
  o.w = bfr(s[6]) | (bfr(s[7]) << 16);
  WF[idx] = o;
}

// ============================================================================
// Pack W_ih [2048][K] fp32 -> bf16 MFMA B-fragments, plain n-tile order:
// frag (nt, ks): lane l holds W[nt*16+(l&15)][ks*32+(l>>4)*8 .. +7].
// ============================================================================
__global__ __launch_bounds__(256) void pack_wih(
    const float* __restrict__ W, uint4* __restrict__ WF, int K) {
  const int idx = blockIdx.x * 256 + threadIdx.x;  // nt*ksn*64 total
  const int ksn = K >> 5;
  const int l  = idx & 63;
  const int ks = (idx >> 6) & (ksn - 1);
  const int nt = idx >> 6 >> (K == 512 ? 4 : 3);
  const int row = nt * 16 + (l & 15);
  const int k0  = ks * 32 + (l >> 4) * 8;
  const float* s = W + (size_t)row * K + k0;
  uint4 o;
  o.x = bfr(s[0]) | (bfr(s[1]) << 16);
  o.y = bfr(s[2]) | (bfr(s[3]) << 16);
  o.z = bfr(s[4]) | (bfr(s[5]) << 16);
  o.w = bfr(s[6]) | (bfr(s[7]) << 16);
  WF[idx] = o;
}

// ============================================================================
// MFMA GEMM (verified round 8): C[m][n] = sum_k A(m)[k]*W[n][k] + b1[n]+b2[n]
// A bf16 row-major [.][K]; row(m) = (m>>4)*T_A + t0 + (m&15). C fp32 [2048].
// Grid 1024, XCD-clustered B-slices (L2-resident). Block 64x64, 4 waves.
// ============================================================================
__global__ __launch_bounds__(256) void gemm_xg_mfma(
    const unsigned short* __restrict__ A, const short8v* __restrict__ WF,
    const float* __restrict__ bias1, const float* __restrict__ bias2,
    float* __restrict__ C, int K, int T_A, int t0) {
  __shared__ uint4 Ash[64 * 64];       // 64KB max (uses 64*(K/8))
  const int bid = blockIdx.x;
  const int xcd = bid & 7;
  const int q   = bid >> 3;
  const int n0  = (xcd * 4 + (q & 3)) * 64;
  const int m0  = (q >> 2) * 64;
  const int tid = threadIdx.x;
  const int ch  = K >> 3;              // uint4 chunks per row (32 or 64)
  const int chl = (K == 512) ? 6 : 5;
  const int ksn = K >> 5;

  const int total = 64 << chl;
  for (int idx = tid; idx < total; idx += 256) {
    const int r = idx >> chl, c = idx & (ch - 1);
    const int m = m0 + r;
    const size_t arow = (size_t)(m >> TC_LOG_) * T_A + t0 + (m & (TC_ - 1));
    Ash[(r << chl) + (c ^ (r & 7))] =
        *(const uint4*)(A + arow * K + c * 8);
  }
  __syncthreads();

  const int lane = tid & 63;
  const int w = tid >> 6;              // wave = 16-col slice
  const int ar = lane & 15;
  const int koct = lane >> 4;
  const int nt = (n0 >> 4) + w;
  const short8v* wf = WF + (size_t)nt * ksn * 64 + lane;
  float4v acc0 = {0,0,0,0}, acc1 = {0,0,0,0}, acc2 = {0,0,0,0}, acc3 = {0,0,0,0};
#pragma unroll 4
  for (int ks = 0; ks < ksn; ++ks) {
    const short8v bv = wf[(size_t)ks * 64];
    const int cc = ks * 4 + koct;
    const short8v a0 = *(const short8v*)&Ash[((ar +  0) << chl) + (cc ^ ((ar +  0) & 7))];
    const short8v a1 = *(const short8v*)&Ash[((ar + 16) << chl) + (cc ^ ((ar + 16) & 7))];
    const short8v a2 = *(const short8v*)&Ash[((ar + 32) << chl) + (cc ^ ((ar + 32) & 7))];
    const short8v a3 = *(const short8v*)&Ash[((ar + 48) << chl) + (cc ^ ((ar + 48) & 7))];
    acc0 = __builtin_amdgcn_mfma_f32_16x16x32_bf16(a0, bv, acc0, 0, 0, 0);
    acc1 = __builtin_amdgcn_mfma_f32_16x16x32_bf16(a1, bv, acc1, 0, 0, 0);
    acc2 = __builtin_amdgcn_mfma_f32_16x16x32_bf16(a2, bv, acc2, 0, 0, 0);
    acc3 = __builtin_amdgcn_mfma_f32_16x16x32_bf16(a3, bv, acc3, 0, 0, 0);
  }
  const int dcol = lane & 15, drow = (lane >> 4) * 4;
  const int n = n0 + w * 16 + dcol;
  const float bs = bias1[n] + bias2[n];
  float* Cb = C + (size_t)(m0 + drow) * G4_ + n;
#pragma unroll
  for (int rr = 0; rr < 4; ++rr) {
    Cb[(size_t)(0 + rr) * G4_]  = acc0[rr] + bs;
    Cb[(size_t)(16 + rr) * G4_] = acc1[rr] + bs;
    Cb[(size_t)(32 + rr) * G4_] = acc2[rr] + bs;
    Cb[(size_t)(48 + rr) * G4_] = acc3[rr] + bs;
  }
}

// ============================================================================
// Fused 2-layer MFMA LSTM step — 8-wave K-split variant.
// mode 0: 512 blocks (L0+L1); 1: 256 L0; 2: 256 L1. 512 threads / 8 waves.
// Wave w = (gate g = w>>1, k-half kh = w&1): 8 x mfma_f32_16x16x32_bf16 over
// its 256-k half -> halved dependent-MFMA chain, 2x waves for latency hiding.
// Gate halves summed via gl[2][...]; tail (threads 0..255) does activations.
// ============================================================================
__global__ __launch_bounds__(512) void lstm_step2(
    const short8v* __restrict__ WF0, const float* __restrict__ xg0,
    const unsigned short* __restrict__ h0p, unsigned short* __restrict__ h0n,
    float* __restrict__ cs0, unsigned short* __restrict__ h0c,
    const short8v* __restrict__ WF1, const float* __restrict__ xg1,
    const unsigned short* __restrict__ h1p, unsigned short* __restrict__ h1n,
    float* __restrict__ cs1, float* __restrict__ h1f, int tl, int mode) {
  __shared__ unsigned short hsh[16 * 512];  // 16KB h tile (bf16, chunk-swizzled)
  __shared__ float gl[2][4][16][17];        // gate tiles per k-half
  const int bid = blockIdx.x;
  const int layer = (mode == 0) ? (bid >> 8) : (mode - 1);
  const int xcd = bid & 7;
  const int ctl = (bid >> 3) & 3;
  const int bt  = (bid >> 5) & 7;
  const int ct  = xcd * 4 + ctl;
  const int b0  = bt * 16;

  const short8v* WF; const float* xg; const unsigned short* hprev;
  unsigned short* hnext; float* cst;
  if (layer == 0) { WF = WF0; xg = xg0; hprev = h0p; hnext = h0n; cst = cs0; }
  else            { WF = WF1; xg = xg1; hprev = h1p; hnext = h1n; cst = cs1; }

  const int tid = threadIdx.x;
  // tail identity + prefetch (threads 0..255 only)
  const int tb = tid >> 4, thc = tid & 15;
  float xi = 0.f, xf = 0.f, xgv = 0.f, xo = 0.f, cin = 0.f;
  int bb = 0, hcol = 0;
  if (tid < 256) {
    bb = b0 + tb;
    hcol = ct * 16 + thc;
    const float* xr = xg + ((size_t)bb * TC_ + tl) * G4_ + hcol;
    xi = xr[0]; xf = xr[512]; xgv = xr[1024]; xo = xr[1536];
    cin = cst[(size_t)bb * H_ + hcol];
  }

  // stage h tile: 16 rows x 64 chunks(16B bf16x8), swizzle chunk c -> c^(r&7)
  const uint4* hp4 = (const uint4*)hprev + (size_t)b0 * 64;
#pragma unroll
  for (int j = 0; j < 2; ++j) {
    const int idx = tid + j * 512;
    const int r = idx >> 6, c = idx & 63;
    *(uint4*)&hsh[(r * 64 + (c ^ (r & 7))) * 8] = hp4[(size_t)r * 64 + c];
  }
  __syncthreads();

  // MFMA: wave (g, kh) -> gate g's 16x16 tile over k-half kh
  const int lane = tid & 63;
  const int w = tid >> 6;
  const int g = w >> 1;
  const int kh = w & 1;
  const int ar = lane & 15;
  const int koct = lane >> 4;
  float4v acc = {0.f, 0.f, 0.f, 0.f};
  const short8v* wf = WF + ((size_t)(ct * 4 + g) * 16) * 64 + lane;
#pragma unroll
  for (int ksl = 0; ksl < 8; ++ksl) {
    const int ks = kh * 8 + ksl;
    const int c16 = ks * 4 + koct;
    const short8v av = *(const short8v*)&hsh[(ar * 64 + (c16 ^ (ar & 7))) * 8];
    const short8v bv = wf[(size_t)ks * 64];
    acc = __builtin_amdgcn_mfma_f32_16x16x32_bf16(av, bv, acc, 0, 0, 0);
  }
  // D layout: col = lane&15, row = (lane>>4)*4 + reg
  const int drow = (lane >> 4) * 4, dcol = lane & 15;
#pragma unroll
  for (int rr = 0; rr < 4; ++rr) gl[kh][g][drow + rr][dcol] = acc[rr];
  __syncthreads();

  // tail: threads 0..255 combine k-halves + 4 gates
  if (tid < 256) {
    const float gi = gl[0][0][tb][thc] + gl[1][0][tb][thc] + xi;
    const float gf = gl[0][1][tb][thc] + gl[1][1][tb][thc] + xf;
    const float gg = gl[0][2][tb][thc] + gl[1][2][tb][thc] + xgv;
    const float go = gl[0][3][tb][thc] + gl[1][3][tb][thc] + xo;
    const float iv = 1.f / (1.f + __expf(-gi));
    const float fv = 1.f / (1.f + __expf(-gf));
    const float gv = tanhf(gg);
    const float ov = 1.f / (1.f + __expf(-go));
    const float cn = fv * cin + iv * gv;
    const float hv = ov * tanhf(cn);
    cst[(size_t)bb * H_ + hcol] = cn;
    const unsigned short hb = (unsigned short)bfr(hv);
    hnext[(size_t)bb * H_ + hcol] = hb;
    if (layer == 0) h0c[((size_t)bb * TC_ + tl) * H_ + hcol] = hb;
    else            h1f[(size_t)bb * H_ + hcol] = hv;
  }
}

// ============================================================================
// Final FC (10 classes) + log_softmax. One wave per batch row (fp32 h).
// ============================================================================
__global__ __launch_bounds__(64) void fc_logsoftmax(
    const float* __restrict__ h, const float* __restrict__ Wfc,
    const float* __restrict__ bfc, float* __restrict__ out) {
  const int b = blockIdx.x, lane = threadIdx.x;
  const float4* h4 = (const float4*)(h + (size_t)b * H_);
  const float4 hv0 = h4[lane * 2], hv1 = h4[lane * 2 + 1];
  float logits[10];
#pragma unroll
  for (int cc = 0; cc < 10; ++cc) {
    const float4* w4 = (const float4*)(Wfc + (size_t)cc * H_);
    const float4 w0 = w4[lane * 2], w1 = w4[lane * 2 + 1];
    float v = hv0.x * w0.x + hv0.y * w0.y + hv0.z * w0.z + hv0.w * w0.w +
              hv1.x * w1.x + hv1.y * w1.y + hv1.z * w1.z + hv1.w * w1.w;
#pragma unroll
    for (int off = 32; off; off >>= 1) v += __shfl_xor(v, off);
    logits[cc] = v + bfc[cc];
  }
  float m = logits[0];
#pragma unroll
  for (int cc = 1; cc < 10; ++cc) m = fmaxf(m, logits[cc]);
  float s = 0.f;
#pragma unroll
  for (int cc = 0; cc < 10; ++cc) s += __expf(logits[cc] - m);
  const float lse = m + __logf(s);
  if (lane < 10) out[(size_t)b * 10 + lane] = logits[lane] - lse;
}

// ============================================================================
extern "C" void kernel_launch(void* const* d_in, const int* in_sizes, int n_in,
                              void* d_out, int out_size, void* d_ws, size_t ws_size,
                              hipStream_t stream) {
  const float* x    = (const float*)d_in[0];
  const float* Wih0 = (const float*)d_in[1];
  const float* Whh0 = (const float*)d_in[2];
  const float* bih0 = (const float*)d_in[3];
  const float* bhh0 = (const float*)d_in[4];
  const float* Wih1 = (const float*)d_in[5];
  const float* Whh1 = (const float*)d_in[6];
  const float* bih1 = (const float*)d_in[7];
  const float* bhh1 = (const float*)d_in[8];
  const float* Wfc  = (const float*)d_in[9];
  const float* bfc  = (const float*)d_in[10];

  float* ws   = (float*)d_ws;
  float* XG0  = ws + OFF_XG0;
  float* XG1  = ws + OFF_XG1;
  unsigned short* h0c = (unsigned short*)(ws + OFF_H0C);
  unsigned short* hb0 = (unsigned short*)(ws + OFF_HB0);
  unsigned short* hb1 = (unsigned short*)(ws + OFF_HB1);
  float* c0   = ws + OFF_C0;
  float* c1   = ws + OFF_C1;
  float* h1f  = ws + OFF_H1F;
  short8v* wf0 = (short8v*)(ws + OFF_WF0);
  short8v* wf1 = (short8v*)(ws + OFF_WF1);
  short8v* wi0 = (short8v*)(ws + OFF_WI0);
  short8v* wi1 = (short8v*)(ws + OFF_WI1);
  unsigned short* xbf = (unsigned short*)(ws + OFF_XBF);

  // zero h ping-pongs + c states; pack weights; convert x to bf16
  hipMemsetAsync(hb0, 0, (OFF_H1F - OFF_HB0) * sizeof(float), stream);
  pack_whh3<<<512, 256, 0, stream>>>(Whh0, (uint4*)wf0);
  pack_whh3<<<512, 256, 0, stream>>>(Whh1, (uint4*)wf1);
  pack_wih<<<256, 256, 0, stream>>>(Wih0, (uint4*)wi0, IN_);
  pack_wih<<<512, 256, 0, stream>>>(Wih1, (uint4*)wi1, H_);
  conv_bf16<<<4096, 256, 0, stream>>>(x, (uint4*)xbf, B_ * T_ * IN_ / 8);

  const size_t BHu = (size_t)B_ * H_;  // bf16 slot stride
  for (int ch = 0; ch < NCHUNK_; ++ch) {
    const int t0 = ch * TC_;
    gemm_xg_mfma<<<1024, 256, 0, stream>>>(xbf, wi0, bih0, bhh0, XG0, IN_, T_, t0);
    if (ch > 0)
      gemm_xg_mfma<<<1024, 256, 0, stream>>>(h0c, wi1, bih1, bhh1, XG1, H_, TC_, 0);
    for (int t = 0; t < TC_; ++t) {
      const int sg0 = t0 + t + 1;        // L0 global step (1-based)
      const int sg1 = sg0 - TC_;         // L1 global step (prev chunk)
      const int mode = (ch == 0) ? 1 : 0;
      const int nblk = (ch == 0) ? 256 : 512;
      lstm_step2<<<nblk, 512, 0, stream>>>(
          wf0, XG0, hb0 + ((sg0 - 1) & 1) * BHu, hb0 + (sg0 & 1) * BHu, c0, h0c,
          wf1, XG1, hb1 + ((sg1 - 1) & 1) * BHu, hb1 + (sg1 & 1) * BHu, c1, h1f,
          t, mode);
    }
  }
  // pipeline drain: L1 over the last chunk
  gemm_xg_mfma<<<1024, 256, 0, stream>>>(h0c, wi1, bih1, bhh1, XG1, H_, TC_, 0);
  for (int t = 0; t < TC_; ++t) {
    const int sg1 = (NCHUNK_ - 1) * TC_ + t + 1;
    lstm_step2<<<256, 512, 0, stream>>>(
        wf0, XG0, hb0, hb0, c0, h0c,
        wf1, XG1, hb1 + ((sg1 - 1) & 1) * BHu, hb1 + (sg1 & 1) * BHu, c1, h1f,
        t, 2);
  }
  fc_logsoftmax<<<dim3(B_), 64, 0, stream>>>(h1f, Wfc, bfc, (float*)d_out);
}